// Round 1
// baseline (457.520 us; speedup 1.0000x reference)
//
#include <hip/hip_runtime.h>
#include <hip/hip_bf16.h>
#include <math.h>

// Problem constants (reference: N=32768, M=8192, Z_DIM=64)
#define NN 32768
#define MM 8192
#define ZD 64
#define BM 64            // e-tile (output cols per block)
#define BN 64            // z-tile (candidates per inner tile)
#define NCHUNKS 16       // split of N across blockIdx.y
#define CHUNK (NN / NCHUNKS)   // 2048

// ---------------------------------------------------------------------------
// Kernel A: zt_t[k][n] = tanh(z[n][k])  (k-major transpose), zn[n] = ||zt_n||^2
// ---------------------------------------------------------------------------
__global__ __launch_bounds__(256) void prep_z_kernel(
    const float* __restrict__ z, float* __restrict__ zt_t,
    float* __restrict__ zn) {
  int n = blockIdx.x * blockDim.x + threadIdx.x;
  if (n >= NN) return;
  float s = 0.f;
#pragma unroll
  for (int q = 0; q < ZD / 4; ++q) {
    float4 v = *reinterpret_cast<const float4*>(&z[(size_t)n * ZD + q * 4]);
    float a0 = tanhf(v.x), a1 = tanhf(v.y), a2 = tanhf(v.z), a3 = tanhf(v.w);
    // writes coalesced across n (consecutive threads -> consecutive addresses)
    zt_t[(size_t)(q * 4 + 0) * NN + n] = a0;
    zt_t[(size_t)(q * 4 + 1) * NN + n] = a1;
    zt_t[(size_t)(q * 4 + 2) * NN + n] = a2;
    zt_t[(size_t)(q * 4 + 3) * NN + n] = a3;
    s += a0 * a0 + a1 * a1 + a2 * a2 + a3 * a3;
  }
  zn[n] = s;
}

// ---------------------------------------------------------------------------
// Kernel A2: e_t[k][m] = e[m][k], en[m] = ||e_m||^2
// ---------------------------------------------------------------------------
__global__ __launch_bounds__(256) void prep_e_kernel(
    const float* __restrict__ e, float* __restrict__ e_t,
    float* __restrict__ en) {
  int m = blockIdx.x * blockDim.x + threadIdx.x;
  if (m >= MM) return;
  float s = 0.f;
#pragma unroll
  for (int q = 0; q < ZD / 4; ++q) {
    float4 v = *reinterpret_cast<const float4*>(&e[(size_t)m * ZD + q * 4]);
    e_t[(size_t)(q * 4 + 0) * MM + m] = v.x;
    e_t[(size_t)(q * 4 + 1) * MM + m] = v.y;
    e_t[(size_t)(q * 4 + 2) * MM + m] = v.z;
    e_t[(size_t)(q * 4 + 3) * MM + m] = v.w;
    s += v.x * v.x + v.y * v.y + v.z * v.z + v.w * v.w;
  }
  en[m] = s;
}

// ---------------------------------------------------------------------------
// Kernel B: for each m in [m0, m0+64), min over n in this block's N-chunk of
//   zn[n] + en[m] - 2 * dot(zt_n, e_m)
// 16x16 threads, 4x4 micro-tile each. k-major LDS tiles, float4 reads.
// ---------------------------------------------------------------------------
__global__ __launch_bounds__(256) void min_dist_kernel(
    const float* __restrict__ zt_t, const float* __restrict__ e_t,
    const float* __restrict__ zn, const float* __restrict__ en,
    float* __restrict__ partial) {
  __shared__ float zlds[ZD][BN + 4];
  __shared__ float elds[ZD][BM + 4];
  __shared__ float red[16][BM];

  const int tx = threadIdx.x & 15;   // m-group
  const int ty = threadIdx.x >> 4;   // n-group
  const int m0 = blockIdx.x * BM;
  const int n_start = blockIdx.y * CHUNK;

  // stage e tile once: elds[k][c] = e_t[k][m0+c]
#pragma unroll
  for (int r = 0; r < ZD; r += 16) {
    int k = r + ty;
    *reinterpret_cast<float4*>(&elds[k][tx * 4]) =
        *reinterpret_cast<const float4*>(&e_t[(size_t)k * MM + m0 + tx * 4]);
  }

  float enr[4];
  *reinterpret_cast<float4*>(enr) =
      *reinterpret_cast<const float4*>(&en[m0 + tx * 4]);

  float minv[4] = {3.4e38f, 3.4e38f, 3.4e38f, 3.4e38f};

  for (int t = 0; t < CHUNK / BN; ++t) {
    const int n_tile = n_start + t * BN;
    __syncthreads();  // protect previous tile's reads
#pragma unroll
    for (int r = 0; r < ZD; r += 16) {
      int k = r + ty;
      *reinterpret_cast<float4*>(&zlds[k][tx * 4]) =
          *reinterpret_cast<const float4*>(&zt_t[(size_t)k * NN + n_tile + tx * 4]);
    }
    __syncthreads();

    float acc[4][4] = {{0.f}};
#pragma unroll 8
    for (int k = 0; k < ZD; ++k) {
      float4 evv = *reinterpret_cast<const float4*>(&elds[k][tx * 4]);
      float4 zvv = *reinterpret_cast<const float4*>(&zlds[k][ty * 4]);
      float ev[4] = {evv.x, evv.y, evv.z, evv.w};
      float zv[4] = {zvv.x, zvv.y, zvv.z, zvv.w};
#pragma unroll
      for (int i = 0; i < 4; ++i)
#pragma unroll
        for (int j = 0; j < 4; ++j) acc[i][j] = fmaf(ev[i], zv[j], acc[i][j]);
    }

    float4 znv4 = *reinterpret_cast<const float4*>(&zn[n_tile + ty * 4]);
    float znv[4] = {znv4.x, znv4.y, znv4.z, znv4.w};
#pragma unroll
    for (int i = 0; i < 4; ++i)
#pragma unroll
      for (int j = 0; j < 4; ++j) {
        float dist = fmaf(-2.f, acc[i][j], znv[j] + enr[i]);
        minv[i] = fminf(minv[i], dist);
      }
  }

  // reduce minv over ty (16 groups) for each m column
  __syncthreads();
#pragma unroll
  for (int i = 0; i < 4; ++i) red[ty][tx * 4 + i] = minv[i];
  __syncthreads();
  if (threadIdx.x < BM) {
    int c = threadIdx.x;
    float mv = red[0][c];
#pragma unroll
    for (int r = 1; r < 16; ++r) mv = fminf(mv, red[r][c]);
    partial[(size_t)blockIdx.y * MM + m0 + c] = mv;
  }
}

// ---------------------------------------------------------------------------
// Kernel C: deterministic final reduce: min over chunks, mean over m
// ---------------------------------------------------------------------------
__global__ __launch_bounds__(256) void finalize_kernel(
    const float* __restrict__ partial, float* __restrict__ out) {
  __shared__ double sred[256];
  double s = 0.0;
  for (int m = threadIdx.x; m < MM; m += 256) {
    float mv = partial[m];
#pragma unroll
    for (int c = 1; c < NCHUNKS; ++c) mv = fminf(mv, partial[(size_t)c * MM + m]);
    s += (double)mv;
  }
  sred[threadIdx.x] = s;
  __syncthreads();
  for (int off = 128; off > 0; off >>= 1) {
    if ((int)threadIdx.x < off) sred[threadIdx.x] += sred[threadIdx.x + off];
    __syncthreads();
  }
  if (threadIdx.x == 0) out[0] = (float)(sred[0] / (double)MM);
}

extern "C" void kernel_launch(void* const* d_in, const int* in_sizes, int n_in,
                              void* d_out, int out_size, void* d_ws, size_t ws_size,
                              hipStream_t stream) {
  const float* z = (const float*)d_in[0];   // (N, 64)
  const float* e = (const float*)d_in[1];   // (M, 64)
  float* out = (float*)d_out;

  float* ws = (float*)d_ws;
  float* zt_t = ws;                                  // ZD*NN
  float* e_t = zt_t + (size_t)ZD * NN;               // ZD*MM
  float* zn = e_t + (size_t)ZD * MM;                 // NN
  float* en = zn + NN;                               // MM
  float* partial = en + MM;                          // NCHUNKS*MM

  prep_z_kernel<<<NN / 256, 256, 0, stream>>>(z, zt_t, zn);
  prep_e_kernel<<<MM / 256, 256, 0, stream>>>(e, e_t, en);
  dim3 grid(MM / BM, NCHUNKS);
  min_dist_kernel<<<grid, 256, 0, stream>>>(zt_t, e_t, zn, en, partial);
  finalize_kernel<<<1, 256, 0, stream>>>(partial, out);
}

// Round 2
// 91.127 us; speedup vs baseline: 5.0207x; 5.0207x over previous
//
#include <hip/hip_runtime.h>
#include <hip/hip_bf16.h>
#include <math.h>

// Problem: N=32768, M=8192, Z=64.  loss = mean_m min_n ||tanh(z_n) - e_m||^2
#define NN 32768
#define MM 8192
#define ZD 64
#define MBLK 128              // m-columns per block
#define NCHUNKS 16            // split of N across blockIdx.y
#define CHUNK (NN / NCHUNKS)  // 2048
#define NITER (CHUNK / 64)    // 32 iters; 64 n per block-iter (16 per wave)

typedef __attribute__((ext_vector_type(8))) short bf16x8;  // 8 bf16 = 4 VGPR
typedef __attribute__((ext_vector_type(4))) float f32x4;

__device__ inline unsigned short f2bf(float f) {  // RNE f32 -> bf16 (finite inputs)
  unsigned u = __float_as_uint(f);
  return (unsigned short)((u + 0x7fffu + ((u >> 16) & 1u)) >> 16);
}
__device__ inline float bf2f(unsigned short h) {
  return __uint_as_float(((unsigned)h) << 16);
}

// ---------------------------------------------------------------------------
// prep_z: zb[n][k] = bf16(tanh(z[n][k])), zn[n] = sum of quantized^2
// ---------------------------------------------------------------------------
__global__ __launch_bounds__(256) void prep_z(const float* __restrict__ z,
                                              unsigned short* __restrict__ zb,
                                              float* __restrict__ zn) {
  int n = blockIdx.x * 256 + threadIdx.x;
  float s = 0.f;
#pragma unroll
  for (int q = 0; q < ZD / 4; ++q) {
    float4 v = *reinterpret_cast<const float4*>(&z[(size_t)n * ZD + q * 4]);
    unsigned short b0 = f2bf(tanhf(v.x)), b1 = f2bf(tanhf(v.y));
    unsigned short b2 = f2bf(tanhf(v.z)), b3 = f2bf(tanhf(v.w));
    float r0 = bf2f(b0), r1 = bf2f(b1), r2 = bf2f(b2), r3 = bf2f(b3);
    s += r0 * r0 + r1 * r1 + r2 * r2 + r3 * r3;
    ushort4 u = {b0, b1, b2, b3};
    *reinterpret_cast<ushort4*>(&zb[(size_t)n * ZD + q * 4]) = u;
  }
  zn[n] = s;
}

// ---------------------------------------------------------------------------
// prep_e: q = bf16(e);  eb[m][k] = bf16(-2*q)  (exact);  en[m] = sum q^2
// ---------------------------------------------------------------------------
__global__ __launch_bounds__(256) void prep_e(const float* __restrict__ e,
                                              unsigned short* __restrict__ eb,
                                              float* __restrict__ en) {
  int m = blockIdx.x * 256 + threadIdx.x;
  float s = 0.f;
#pragma unroll
  for (int q = 0; q < ZD / 4; ++q) {
    float4 v = *reinterpret_cast<const float4*>(&e[(size_t)m * ZD + q * 4]);
    unsigned short q0 = f2bf(v.x), q1 = f2bf(v.y), q2 = f2bf(v.z), q3 = f2bf(v.w);
    float r0 = bf2f(q0), r1 = bf2f(q1), r2 = bf2f(q2), r3 = bf2f(q3);
    s += r0 * r0 + r1 * r1 + r2 * r2 + r3 * r3;
    ushort4 u = {f2bf(-2.f * r0), f2bf(-2.f * r1), f2bf(-2.f * r2), f2bf(-2.f * r3)};
    *reinterpret_cast<ushort4*>(&eb[(size_t)m * ZD + q * 4]) = u;
  }
  en[m] = s;
}

// ---------------------------------------------------------------------------
// min_dist: partial[chunk][m] = min over n-in-chunk of ( zn[n] - 2*zt_n.e_m )
// (en[m] added in finalize; constant over n so argmin unaffected)
// 4 waves/block, no LDS in main loop, operands direct from L2/L3.
// Per wave-iter: A = 16 z-rows (K=64 in 2 halves), B = 8 e-tiles of 16 cols.
// ---------------------------------------------------------------------------
__global__ __launch_bounds__(256) void min_dist(
    const unsigned short* __restrict__ zb, const unsigned short* __restrict__ eb,
    const float* __restrict__ zn, float* __restrict__ partial) {
  const int lane = threadIdx.x & 63;
  const int wv = threadIdx.x >> 6;   // 0..3
  const int lr = lane & 15;          // row/col within fragment
  const int lg = lane >> 4;          // 0..3 k-group
  const int m0 = blockIdx.x * MBLK;
  const int nb0 = blockIdx.y * CHUNK;

  // e fragments: resident in registers for the whole kernel (64 VGPRs)
  bf16x8 bfr[8][2];
#pragma unroll
  for (int t = 0; t < 8; ++t)
#pragma unroll
    for (int h = 0; h < 2; ++h)
      bfr[t][h] = *reinterpret_cast<const bf16x8*>(
          &eb[(size_t)(m0 + t * 16 + lr) * ZD + h * 32 + lg * 8]);

  f32x4 minv[8];
#pragma unroll
  for (int t = 0; t < 8; ++t)
    minv[t] = (f32x4){3.4e38f, 3.4e38f, 3.4e38f, 3.4e38f};
  const f32x4 zero4 = (f32x4){0.f, 0.f, 0.f, 0.f};

#pragma unroll 2
  for (int it = 0; it < NITER; ++it) {
    const int nb = nb0 + it * 64 + wv * 16;
    const size_t zrow = (size_t)(nb + lr) * ZD;
    bf16x8 afr0 = *reinterpret_cast<const bf16x8*>(&zb[zrow + lg * 8]);
    bf16x8 afr1 = *reinterpret_cast<const bf16x8*>(&zb[zrow + 32 + lg * 8]);
    f32x4 znv = *reinterpret_cast<const f32x4*>(&zn[nb + lg * 4]);
#pragma unroll
    for (int t = 0; t < 8; ++t) {
      f32x4 acc = __builtin_amdgcn_mfma_f32_16x16x32_bf16(afr0, bfr[t][0], zero4, 0, 0, 0);
      acc = __builtin_amdgcn_mfma_f32_16x16x32_bf16(afr1, bfr[t][1], acc, 0, 0, 0);
      // D layout: col = lane&15 -> m, row = (lane>>4)*4 + r -> n  (m89/m91)
#pragma unroll
      for (int r = 0; r < 4; ++r)
        minv[t][r] = fminf(minv[t][r], acc[r] + znv[r]);
    }
  }

  // reduce: in-lane over 4 rows, cross-lane over the 4 row-groups
  __shared__ float red[4][MBLK];
#pragma unroll
  for (int t = 0; t < 8; ++t) {
    float v = fminf(fminf(minv[t][0], minv[t][1]), fminf(minv[t][2], minv[t][3]));
    v = fminf(v, __shfl_xor(v, 16, 64));
    v = fminf(v, __shfl_xor(v, 32, 64));
    if (lg == 0) red[wv][t * 16 + lr] = v;  // lanes 0..15 hold col lr
  }
  __syncthreads();
  if (threadIdx.x < MBLK) {
    int c = threadIdx.x;
    float mv = fminf(fminf(red[0][c], red[1][c]), fminf(red[2][c], red[3][c]));
    partial[(size_t)blockIdx.y * MM + m0 + c] = mv;
  }
}

// ---------------------------------------------------------------------------
// finalize: loss = mean_m ( en[m] + min_c partial[c][m] )
// ---------------------------------------------------------------------------
__global__ __launch_bounds__(256) void finalize(const float* __restrict__ partial,
                                                const float* __restrict__ en,
                                                float* __restrict__ out) {
  __shared__ double sred[256];
  double s = 0.0;
  for (int m = threadIdx.x; m < MM; m += 256) {
    float mv = partial[m];
#pragma unroll
    for (int c = 1; c < NCHUNKS; ++c)
      mv = fminf(mv, partial[(size_t)c * MM + m]);
    s += (double)(mv + en[m]);
  }
  sred[threadIdx.x] = s;
  __syncthreads();
  for (int off = 128; off > 0; off >>= 1) {
    if ((int)threadIdx.x < off) sred[threadIdx.x] += sred[threadIdx.x + off];
    __syncthreads();
  }
  if (threadIdx.x == 0) out[0] = (float)(sred[0] / (double)MM);
}

extern "C" void kernel_launch(void* const* d_in, const int* in_sizes, int n_in,
                              void* d_out, int out_size, void* d_ws, size_t ws_size,
                              hipStream_t stream) {
  const float* z = (const float*)d_in[0];  // (N, 64) f32
  const float* e = (const float*)d_in[1];  // (M, 64) f32
  float* out = (float*)d_out;

  unsigned short* zb = (unsigned short*)d_ws;          // NN*64 bf16
  unsigned short* eb = zb + (size_t)NN * ZD;           // MM*64 bf16
  float* zn = (float*)(eb + (size_t)MM * ZD);          // NN f32
  float* en = zn + NN;                                 // MM f32
  float* partial = en + MM;                            // NCHUNKS*MM f32

  prep_z<<<NN / 256, 256, 0, stream>>>(z, zb, zn);
  prep_e<<<MM / 256, 256, 0, stream>>>(e, eb, en);
  dim3 grid(MM / MBLK, NCHUNKS);
  min_dist<<<grid, 256, 0, stream>>>(zb, eb, zn, partial);
  finalize<<<1, 256, 0, stream>>>(partial, en, out);
}

// Round 3
// 74.268 us; speedup vs baseline: 6.1604x; 1.2270x over previous
//
#include <hip/hip_runtime.h>
#include <hip/hip_bf16.h>
#include <math.h>

// Problem: N=32768, M=8192, Z=64.  loss = mean_m min_n ||tanh(z_n) - e_m||^2
#define NN 32768
#define MM 8192
#define ZD 64
#define MBLK 128              // m-columns per block
#define NCHUNKS 32            // split of N across blockIdx.y
#define CHUNK (NN / NCHUNKS)  // 1024
#define NITER (CHUNK / 64)    // 16 iters; 64 n per block-iter (16 per wave)

typedef __attribute__((ext_vector_type(8))) short bf16x8;  // 8 bf16 = 4 VGPR
typedef __attribute__((ext_vector_type(4))) float f32x4;

__device__ inline unsigned short f2bf(float f) {  // RNE f32 -> bf16 (finite)
  unsigned u = __float_as_uint(f);
  return (unsigned short)((u + 0x7fffu + ((u >> 16) & 1u)) >> 16);
}
__device__ inline float bf2f(unsigned short h) {
  return __uint_as_float(((unsigned)h) << 16);
}

// ---------------------------------------------------------------------------
// prep_z: zb[n][k] = bf16(tanh(z[n][k])), zn[n] = sum(quantized^2)
// 8 threads per row: coalesced 32B loads, 16B stores.
// ---------------------------------------------------------------------------
__global__ __launch_bounds__(256) void prep_z(const float* __restrict__ z,
                                              unsigned short* __restrict__ zb,
                                              float* __restrict__ zn) {
  const int row = blockIdx.x * 32 + (threadIdx.x >> 3);
  const int q = threadIdx.x & 7;  // 8 f32 each
  const size_t base = (size_t)row * ZD + q * 8;
  float4 v0 = *reinterpret_cast<const float4*>(&z[base]);
  float4 v1 = *reinterpret_cast<const float4*>(&z[base + 4]);
  float in[8] = {v0.x, v0.y, v0.z, v0.w, v1.x, v1.y, v1.z, v1.w};
  unsigned short b[8];
  float s = 0.f;
#pragma unroll
  for (int i = 0; i < 8; ++i) {
    b[i] = f2bf(tanhf(in[i]));
    float r = bf2f(b[i]);
    s += r * r;
  }
  *reinterpret_cast<bf16x8*>(&zb[base]) = *reinterpret_cast<bf16x8*>(b);
  s += __shfl_xor(s, 1, 64);
  s += __shfl_xor(s, 2, 64);
  s += __shfl_xor(s, 4, 64);
  if (q == 0) zn[row] = s;
}

// ---------------------------------------------------------------------------
// prep_e: qk = bf16(e); eb[m][k] = bf16(-2*qk) (exact); en[m] = sum qk^2
// ---------------------------------------------------------------------------
__global__ __launch_bounds__(256) void prep_e(const float* __restrict__ e,
                                              unsigned short* __restrict__ eb,
                                              float* __restrict__ en) {
  const int row = blockIdx.x * 32 + (threadIdx.x >> 3);
  const int q = threadIdx.x & 7;
  const size_t base = (size_t)row * ZD + q * 8;
  float4 v0 = *reinterpret_cast<const float4*>(&e[base]);
  float4 v1 = *reinterpret_cast<const float4*>(&e[base + 4]);
  float in[8] = {v0.x, v0.y, v0.z, v0.w, v1.x, v1.y, v1.z, v1.w};
  unsigned short b[8];
  float s = 0.f;
#pragma unroll
  for (int i = 0; i < 8; ++i) {
    unsigned short qb = f2bf(in[i]);
    float r = bf2f(qb);
    s += r * r;
    b[i] = f2bf(-2.f * r);  // exact: power-of-2 scale + sign
  }
  *reinterpret_cast<bf16x8*>(&eb[base]) = *reinterpret_cast<bf16x8*>(b);
  s += __shfl_xor(s, 1, 64);
  s += __shfl_xor(s, 2, 64);
  s += __shfl_xor(s, 4, 64);
  if (q == 0) en[row] = s;
}

// ---------------------------------------------------------------------------
// min_dist: partial[chunk][m] = min over n-in-chunk of ( zn[n] - 2*z_n.e_m )
// zn folded into the MFMA C-operand (zn depends only on row=n of the C/D
// fragment layout). Epilogue = 4 fmin per 16x16 tile.
// ---------------------------------------------------------------------------
__global__ __launch_bounds__(256) void min_dist(
    const unsigned short* __restrict__ zb, const unsigned short* __restrict__ eb,
    const float* __restrict__ zn, float* __restrict__ partial) {
  const int lane = threadIdx.x & 63;
  const int wv = threadIdx.x >> 6;   // 0..3
  const int lr = lane & 15;          // fragment row/col
  const int lg = lane >> 4;          // 0..3 k-group
  const int m0 = blockIdx.x * MBLK;
  const int nb0 = blockIdx.y * CHUNK;

  // e fragments resident in registers (64 VGPRs)
  bf16x8 bfr[8][2];
#pragma unroll
  for (int t = 0; t < 8; ++t)
#pragma unroll
    for (int h = 0; h < 2; ++h)
      bfr[t][h] = *reinterpret_cast<const bf16x8*>(
          &eb[(size_t)(m0 + t * 16 + lr) * ZD + h * 32 + lg * 8]);

  f32x4 minv[8];
#pragma unroll
  for (int t = 0; t < 8; ++t)
    minv[t] = (f32x4){3.4e38f, 3.4e38f, 3.4e38f, 3.4e38f};

#pragma unroll 2
  for (int it = 0; it < NITER; ++it) {
    const int nb = nb0 + it * 64 + wv * 16;
    const size_t zrow = (size_t)(nb + lr) * ZD;
    bf16x8 afr0 = *reinterpret_cast<const bf16x8*>(&zb[zrow + lg * 8]);
    bf16x8 afr1 = *reinterpret_cast<const bf16x8*>(&zb[zrow + 32 + lg * 8]);
    f32x4 znv = *reinterpret_cast<const f32x4*>(&zn[nb + lg * 4]);
#pragma unroll
    for (int t = 0; t < 8; ++t) {
      // C-in = znv: acc = zn[n] + sum_k A*B   (A=z row n, B=-2*e col m)
      f32x4 acc = __builtin_amdgcn_mfma_f32_16x16x32_bf16(afr0, bfr[t][0], znv, 0, 0, 0);
      acc = __builtin_amdgcn_mfma_f32_16x16x32_bf16(afr1, bfr[t][1], acc, 0, 0, 0);
#pragma unroll
      for (int r = 0; r < 4; ++r) minv[t][r] = fminf(minv[t][r], acc[r]);
    }
  }

  // reduce: in-lane over 4 rows, cross-lane over the 4 row-groups
  __shared__ float red[4][MBLK];
#pragma unroll
  for (int t = 0; t < 8; ++t) {
    float v = fminf(fminf(minv[t][0], minv[t][1]), fminf(minv[t][2], minv[t][3]));
    v = fminf(v, __shfl_xor(v, 16, 64));
    v = fminf(v, __shfl_xor(v, 32, 64));
    if (lg == 0) red[wv][t * 16 + lr] = v;
  }
  __syncthreads();
  if (threadIdx.x < MBLK) {
    int c = threadIdx.x;
    float mv = fminf(fminf(red[0][c], red[1][c]), fminf(red[2][c], red[3][c]));
    partial[(size_t)blockIdx.y * MM + m0 + c] = mv;
  }
}

// ---------------------------------------------------------------------------
// finalize1: 32 blocks x 256 m-cols: bsum[b] = sum_m ( en[m] + min_c partial )
// finalize2: out = (sum_b bsum[b]) / M
// ---------------------------------------------------------------------------
__global__ __launch_bounds__(256) void finalize1(const float* __restrict__ partial,
                                                 const float* __restrict__ en,
                                                 double* __restrict__ bsum) {
  const int m = blockIdx.x * 256 + threadIdx.x;
  float mv = partial[m];
#pragma unroll
  for (int c = 1; c < NCHUNKS; ++c)
    mv = fminf(mv, partial[(size_t)c * MM + m]);
  double s = (double)(mv + en[m]);
  __shared__ double sred[256];
  sred[threadIdx.x] = s;
  __syncthreads();
  for (int off = 128; off > 0; off >>= 1) {
    if ((int)threadIdx.x < off) sred[threadIdx.x] += sred[threadIdx.x + off];
    __syncthreads();
  }
  if (threadIdx.x == 0) bsum[blockIdx.x] = sred[0];
}

__global__ __launch_bounds__(64) void finalize2(const double* __restrict__ bsum,
                                                float* __restrict__ out) {
  double s = (threadIdx.x < MM / 256) ? bsum[threadIdx.x] : 0.0;
  s += __shfl_xor(s, 1, 64);
  s += __shfl_xor(s, 2, 64);
  s += __shfl_xor(s, 4, 64);
  s += __shfl_xor(s, 8, 64);
  s += __shfl_xor(s, 16, 64);
  s += __shfl_xor(s, 32, 64);
  if (threadIdx.x == 0) out[0] = (float)(s / (double)MM);
}

extern "C" void kernel_launch(void* const* d_in, const int* in_sizes, int n_in,
                              void* d_out, int out_size, void* d_ws, size_t ws_size,
                              hipStream_t stream) {
  const float* z = (const float*)d_in[0];  // (N, 64) f32
  const float* e = (const float*)d_in[1];  // (M, 64) f32
  float* out = (float*)d_out;

  unsigned short* zb = (unsigned short*)d_ws;          // NN*64 bf16
  unsigned short* eb = zb + (size_t)NN * ZD;           // MM*64 bf16
  float* zn = (float*)(eb + (size_t)MM * ZD);          // NN f32
  float* en = zn + NN;                                 // MM f32
  float* partial = en + MM;                            // NCHUNKS*MM f32
  double* bsum = (double*)(partial + (size_t)NCHUNKS * MM);  // 32 f64

  prep_z<<<NN / 32, 256, 0, stream>>>(z, zb, zn);
  prep_e<<<MM / 32, 256, 0, stream>>>(e, eb, en);
  dim3 grid(MM / MBLK, NCHUNKS);
  min_dist<<<grid, 256, 0, stream>>>(zb, eb, zn, partial);
  finalize1<<<MM / 256, 256, 0, stream>>>(partial, en, bsum);
  finalize2<<<1, 64, 0, stream>>>(bsum, out);
}

// Round 4
// 55.247 us; speedup vs baseline: 8.2813x; 1.3443x over previous
//
#include <hip/hip_runtime.h>
#include <hip/hip_bf16.h>
#include <math.h>

// Problem: N=32768, M=8192, Z=64.  loss = mean_m min_n ||tanh(z_n) - e_m||^2
#define NN 32768
#define MM 8192
#define ZD 64
#define WAVES 4
#define MW 128                 // m-cols per wave
#define MBLK (WAVES * MW)      // 512 m-cols per block
#define NCHUNKS 32             // split of N across blockIdx.y
#define CHUNK (NN / NCHUNKS)   // 1024
#define NROWS 64               // n-rows staged per iteration
#define NITER (CHUNK / NROWS)  // 16

typedef __attribute__((ext_vector_type(8))) short bf16x8;  // 8 bf16 = 4 VGPR
typedef __attribute__((ext_vector_type(4))) float f32x4;

__device__ inline unsigned short f2bf(float f) {  // RNE f32 -> bf16 (finite)
  unsigned u = __float_as_uint(f);
  return (unsigned short)((u + 0x7fffu + ((u >> 16) & 1u)) >> 16);
}
__device__ inline float bf2f(unsigned short h) {
  return __uint_as_float(((unsigned)h) << 16);
}

// ---------------------------------------------------------------------------
// prep_z: zb[n][k] = bf16(tanh(z[n][k])), zn[n] = sum(quantized^2)
// ---------------------------------------------------------------------------
__global__ __launch_bounds__(256) void prep_z(const float* __restrict__ z,
                                              unsigned short* __restrict__ zb,
                                              float* __restrict__ zn) {
  const int row = blockIdx.x * 32 + (threadIdx.x >> 3);
  const int q = threadIdx.x & 7;  // 8 f32 each
  const size_t base = (size_t)row * ZD + q * 8;
  float4 v0 = *reinterpret_cast<const float4*>(&z[base]);
  float4 v1 = *reinterpret_cast<const float4*>(&z[base + 4]);
  float in[8] = {v0.x, v0.y, v0.z, v0.w, v1.x, v1.y, v1.z, v1.w};
  unsigned short b[8];
  float s = 0.f;
#pragma unroll
  for (int i = 0; i < 8; ++i) {
    b[i] = f2bf(tanhf(in[i]));
    float r = bf2f(b[i]);
    s += r * r;
  }
  *reinterpret_cast<bf16x8*>(&zb[base]) = *reinterpret_cast<bf16x8*>(b);
  s += __shfl_xor(s, 1, 64);
  s += __shfl_xor(s, 2, 64);
  s += __shfl_xor(s, 4, 64);
  if (q == 0) zn[row] = s;
}

// ---------------------------------------------------------------------------
// prep_e: qk = bf16(e); eb[m][k] = bf16(-2*qk) (exact); en[m] = sum qk^2
// ---------------------------------------------------------------------------
__global__ __launch_bounds__(256) void prep_e(const float* __restrict__ e,
                                              unsigned short* __restrict__ eb,
                                              float* __restrict__ en) {
  const int row = blockIdx.x * 32 + (threadIdx.x >> 3);
  const int q = threadIdx.x & 7;
  const size_t base = (size_t)row * ZD + q * 8;
  float4 v0 = *reinterpret_cast<const float4*>(&e[base]);
  float4 v1 = *reinterpret_cast<const float4*>(&e[base + 4]);
  float in[8] = {v0.x, v0.y, v0.z, v0.w, v1.x, v1.y, v1.z, v1.w};
  unsigned short b[8];
  float s = 0.f;
#pragma unroll
  for (int i = 0; i < 8; ++i) {
    unsigned short qb = f2bf(in[i]);
    float r = bf2f(qb);
    s += r * r;
    b[i] = f2bf(-2.f * r);  // exact: power-of-2 scale + sign
  }
  *reinterpret_cast<bf16x8*>(&eb[base]) = *reinterpret_cast<bf16x8*>(b);
  s += __shfl_xor(s, 1, 64);
  s += __shfl_xor(s, 2, 64);
  s += __shfl_xor(s, 4, 64);
  if (q == 0) en[row] = s;
}

// ---------------------------------------------------------------------------
// min_dist: partial[chunk][m] = min over n-in-chunk of ( zn[n] - 2*z_n.e_m )
// 4 waves x 128 m-cols each (512 per block). A-tile (64 n-rows) shared via
// LDS: global_load_lds(16B) double-buffered, XOR-swizzled (linear LDS dest +
// inverse-swizzled global source + swizzled ds_read_b128). zn folded into
// the MFMA C-operand. Per-wave epilogue, no cross-wave reduce.
// ---------------------------------------------------------------------------
__global__ __launch_bounds__(256) void min_dist(
    const unsigned short* __restrict__ zb, const unsigned short* __restrict__ eb,
    const float* __restrict__ zn, float* __restrict__ partial) {
  __shared__ __align__(128) unsigned short zlds[2][NROWS * ZD];  // 2 x 8 KB
  const int lane = threadIdx.x & 63;
  const int wv = threadIdx.x >> 6;   // 0..3
  const int lr = lane & 15;          // fragment row/col
  const int lg = lane >> 4;          // 0..3 k-group
  const int m0 = blockIdx.x * MBLK + wv * MW;
  const int nb0 = blockIdx.y * CHUNK;

  // staging geometry: 8 x 1KB pieces/iter, 2 per wave. Piece i covers rows
  // [i*8, i*8+8). Lane l writes LDS byte i*1024 + l*16 (linear); its source
  // is pre-inverse-swizzled so that reads can apply slot ^= (row&7).
  const int srow = lane >> 3;           // row within piece, 0..7
  const int sslot = (lane & 7) ^ srow;  // inverse-swizzled 16B slot

  // B fragments: 8 tiles of 16 m-cols, K=64 in two halves (64 VGPR)
  bf16x8 bfr[8][2];
#pragma unroll
  for (int t = 0; t < 8; ++t)
#pragma unroll
    for (int h = 0; h < 2; ++h)
      bfr[t][h] = *reinterpret_cast<const bf16x8*>(
          &eb[(size_t)(m0 + t * 16 + lr) * ZD + h * 32 + lg * 8]);

  f32x4 minv[8];
#pragma unroll
  for (int t = 0; t < 8; ++t)
    minv[t] = (f32x4){3.4e38f, 3.4e38f, 3.4e38f, 3.4e38f};

  auto stage = [&](int buf, int nb) {
#pragma unroll
    for (int j = 0; j < 2; ++j) {
      const int i = wv * 2 + j;
      const char* src = (const char*)zb +
          (size_t)(nb + i * 8 + srow) * 128 + (sslot << 4);
      char* dst = (char*)&zlds[buf][0] + i * 1024;
      __builtin_amdgcn_global_load_lds(
          (const __attribute__((address_space(1))) unsigned int*)src,
          (__attribute__((address_space(3))) unsigned int*)dst, 16, 0, 0);
    }
  };

  stage(0, nb0);
  __syncthreads();  // compiler emits vmcnt(0) drain before s_barrier

  for (int it = 0; it < NITER; ++it) {
    const int buf = it & 1;
    if (it + 1 < NITER) stage(buf ^ 1, nb0 + (it + 1) * NROWS);
    const char* lbase = (const char*)&zlds[buf][0];
#pragma unroll
    for (int s = 0; s < 4; ++s) {
      const int rb = (s * 16 + lr) * 128;
      const int x0 = (lg * 16) ^ ((lr & 7) << 4);
      bf16x8 a0 = *reinterpret_cast<const bf16x8*>(lbase + rb + x0);
      bf16x8 a1 = *reinterpret_cast<const bf16x8*>(lbase + rb + (x0 ^ 64));
      f32x4 znv = *reinterpret_cast<const f32x4*>(
          &zn[nb0 + it * NROWS + s * 16 + lg * 4]);
#pragma unroll
      for (int t = 0; t < 8; ++t) {
        // acc = zn[n] + sum_k z_n[k] * (-2 e_m[k])
        f32x4 acc = __builtin_amdgcn_mfma_f32_16x16x32_bf16(a0, bfr[t][0], znv, 0, 0, 0);
        acc = __builtin_amdgcn_mfma_f32_16x16x32_bf16(a1, bfr[t][1], acc, 0, 0, 0);
#pragma unroll
        for (int r = 0; r < 4; ++r) minv[t][r] = fminf(minv[t][r], acc[r]);
      }
    }
    __syncthreads();  // next-stage landed; buf safe to overwrite next round
  }

  // per-wave reduction: in-lane over 4 rows, cross-lane over 4 row-groups
#pragma unroll
  for (int t = 0; t < 8; ++t) {
    float v = fminf(fminf(minv[t][0], minv[t][1]), fminf(minv[t][2], minv[t][3]));
    v = fminf(v, __shfl_xor(v, 16, 64));
    v = fminf(v, __shfl_xor(v, 32, 64));
    if (lg == 0) partial[(size_t)blockIdx.y * MM + m0 + t * 16 + lr] = v;
  }
}

// ---------------------------------------------------------------------------
// finalize1: 32 blocks x 256 m-cols: bsum[b] = sum_m ( en[m] + min_c partial )
// finalize2: out = (sum_b bsum[b]) / M
// ---------------------------------------------------------------------------
__global__ __launch_bounds__(256) void finalize1(const float* __restrict__ partial,
                                                 const float* __restrict__ en,
                                                 double* __restrict__ bsum) {
  const int m = blockIdx.x * 256 + threadIdx.x;
  float mv = partial[m];
#pragma unroll
  for (int c = 1; c < NCHUNKS; ++c)
    mv = fminf(mv, partial[(size_t)c * MM + m]);
  double s = (double)(mv + en[m]);
  __shared__ double sred[256];
  sred[threadIdx.x] = s;
  __syncthreads();
  for (int off = 128; off > 0; off >>= 1) {
    if ((int)threadIdx.x < off) sred[threadIdx.x] += sred[threadIdx.x + off];
    __syncthreads();
  }
  if (threadIdx.x == 0) bsum[blockIdx.x] = sred[0];
}

__global__ __launch_bounds__(64) void finalize2(const double* __restrict__ bsum,
                                                float* __restrict__ out) {
  double s = (threadIdx.x < MM / 256) ? bsum[threadIdx.x] : 0.0;
  s += __shfl_xor(s, 1, 64);
  s += __shfl_xor(s, 2, 64);
  s += __shfl_xor(s, 4, 64);
  s += __shfl_xor(s, 8, 64);
  s += __shfl_xor(s, 16, 64);
  s += __shfl_xor(s, 32, 64);
  if (threadIdx.x == 0) out[0] = (float)(s / (double)MM);
}

extern "C" void kernel_launch(void* const* d_in, const int* in_sizes, int n_in,
                              void* d_out, int out_size, void* d_ws, size_t ws_size,
                              hipStream_t stream) {
  const float* z = (const float*)d_in[0];  // (N, 64) f32
  const float* e = (const float*)d_in[1];  // (M, 64) f32
  float* out = (float*)d_out;

  unsigned short* zb = (unsigned short*)d_ws;          // NN*64 bf16 (4 MB)
  unsigned short* eb = zb + (size_t)NN * ZD;           // MM*64 bf16 (1 MB)
  float* zn = (float*)(eb + (size_t)MM * ZD);          // NN f32
  float* en = zn + NN;                                 // MM f32
  float* partial = en + MM;                            // NCHUNKS*MM f32
  double* bsum = (double*)(partial + (size_t)NCHUNKS * MM);  // 32 f64

  prep_z<<<NN / 32, 256, 0, stream>>>(z, zb, zn);
  prep_e<<<MM / 32, 256, 0, stream>>>(e, eb, en);
  dim3 grid(MM / MBLK, NCHUNKS);
  min_dist<<<grid, 256, 0, stream>>>(zb, eb, zn, partial);
  finalize1<<<MM / 256, 256, 0, stream>>>(partial, en, bsum);
  finalize2<<<1, 64, 0, stream>>>(bsum, out);
}

// Round 5
// 49.220 us; speedup vs baseline: 9.2955x; 1.1225x over previous
//
#include <hip/hip_runtime.h>
#include <hip/hip_bf16.h>
#include <math.h>

// Problem: N=32768, M=8192, Z=64.  loss = mean_m min_n ||tanh(z_n) - e_m||^2
#define NN 32768
#define MM 8192
#define ZD 64
#define WAVES 4
#define MW 64                  // m-cols per wave
#define MBLK (WAVES * MW)      // 256 m-cols per block
#define NMB (MM / MBLK)        // 32 m-blocks
#define NCHUNKS 32             // split of N across chunks
#define CHUNK (NN / NCHUNKS)   // 1024
#define NROWS 64               // n-rows staged per iteration
#define NITER (CHUNK / NROWS)  // 16

typedef __attribute__((ext_vector_type(8))) short bf16x8;  // 8 bf16 = 4 VGPR
typedef __attribute__((ext_vector_type(4))) float f32x4;

__device__ inline unsigned short f2bf(float f) {  // RNE f32 -> bf16 (finite)
  unsigned u = __float_as_uint(f);
  return (unsigned short)((u + 0x7fffu + ((u >> 16) & 1u)) >> 16);
}
__device__ inline float bf2f(unsigned short h) {
  return __uint_as_float(((unsigned)h) << 16);
}

// ---------------------------------------------------------------------------
// prep_z: zb[n][k] = bf16(tanh(z[n][k])), zn[n] = sum(quantized^2)
// ---------------------------------------------------------------------------
__global__ __launch_bounds__(256) void prep_z(const float* __restrict__ z,
                                              unsigned short* __restrict__ zb,
                                              float* __restrict__ zn) {
  const int row = blockIdx.x * 32 + (threadIdx.x >> 3);
  const int q = threadIdx.x & 7;  // 8 f32 each
  const size_t base = (size_t)row * ZD + q * 8;
  float4 v0 = *reinterpret_cast<const float4*>(&z[base]);
  float4 v1 = *reinterpret_cast<const float4*>(&z[base + 4]);
  float in[8] = {v0.x, v0.y, v0.z, v0.w, v1.x, v1.y, v1.z, v1.w};
  unsigned short b[8];
  float s = 0.f;
#pragma unroll
  for (int i = 0; i < 8; ++i) {
    b[i] = f2bf(tanhf(in[i]));
    float r = bf2f(b[i]);
    s += r * r;
  }
  *reinterpret_cast<bf16x8*>(&zb[base]) = *reinterpret_cast<bf16x8*>(b);
  s += __shfl_xor(s, 1, 64);
  s += __shfl_xor(s, 2, 64);
  s += __shfl_xor(s, 4, 64);
  if (q == 0) zn[row] = s;
}

// ---------------------------------------------------------------------------
// prep_e: qk = bf16(e); eb[m][k] = bf16(-2*qk) (exact); en[m] = sum qk^2
// ---------------------------------------------------------------------------
__global__ __launch_bounds__(256) void prep_e(const float* __restrict__ e,
                                              unsigned short* __restrict__ eb,
                                              float* __restrict__ en) {
  const int row = blockIdx.x * 32 + (threadIdx.x >> 3);
  const int q = threadIdx.x & 7;
  const size_t base = (size_t)row * ZD + q * 8;
  float4 v0 = *reinterpret_cast<const float4*>(&e[base]);
  float4 v1 = *reinterpret_cast<const float4*>(&e[base + 4]);
  float in[8] = {v0.x, v0.y, v0.z, v0.w, v1.x, v1.y, v1.z, v1.w};
  unsigned short b[8];
  float s = 0.f;
#pragma unroll
  for (int i = 0; i < 8; ++i) {
    unsigned short qb = f2bf(in[i]);
    float r = bf2f(qb);
    s += r * r;
    b[i] = f2bf(-2.f * r);  // exact: power-of-2 scale + sign
  }
  *reinterpret_cast<bf16x8*>(&eb[base]) = *reinterpret_cast<bf16x8*>(b);
  s += __shfl_xor(s, 1, 64);
  s += __shfl_xor(s, 2, 64);
  s += __shfl_xor(s, 4, 64);
  if (q == 0) en[row] = s;
}

// ---------------------------------------------------------------------------
// min_dist: partial[chunk][m] = min over n-in-chunk of ( zn[n] - 2*z_n.e_m )
// 1024 blocks (4/CU), 4 waves x 64 m-cols. A-tile (64 n-rows) shared via LDS:
// global_load_lds(16B) double-buffered, XOR-swizzled (linear LDS dest +
// inverse-swizzled global source + swizzled ds_read_b128). zn folded into the
// MFMA C-operand. XCD-bijective block remap: each XCD owns 4 whole chunks.
// ---------------------------------------------------------------------------
__global__ __launch_bounds__(256, 4) void min_dist(
    const unsigned short* __restrict__ zb, const unsigned short* __restrict__ eb,
    const float* __restrict__ zn, float* __restrict__ partial) {
  __shared__ __align__(128) unsigned short zlds[2][NROWS * ZD];  // 2 x 8 KB
  // XCD-contiguous remap (grid = 1024, 1024 % 8 == 0 -> bijective):
  const int wg = ((blockIdx.x & 7) << 7) + (blockIdx.x >> 3);
  const int mb = wg & (NMB - 1);   // m-block 0..31
  const int cb = wg >> 5;          // chunk 0..31  (4 consecutive per XCD)
  const int lane = threadIdx.x & 63;
  const int wv = threadIdx.x >> 6;   // 0..3
  const int lr = lane & 15;          // fragment row/col
  const int lg = lane >> 4;          // 0..3 k-group
  const int m0 = mb * MBLK + wv * MW;
  const int nb0 = cb * CHUNK;

  // staging geometry: 8 x 1KB pieces/iter (8 rows each), 2 per wave.
  // Lane l writes LDS byte i*1024 + l*16 (linear dest); source is
  // inverse-swizzled so reads can apply slot ^= (row&7).
  const int srow = lane >> 3;           // row within piece, 0..7
  const int sslot = (lane & 7) ^ srow;  // inverse-swizzled 16B slot
  const char* zsrc = (const char*)zb + (size_t)nb0 * 128 +
                     (wv * 16 + srow) * 128 + (sslot << 4);
  char* ldst0 = (char*)&zlds[0][0] + wv * 2048;
  char* ldst1 = (char*)&zlds[1][0] + wv * 2048;

  // B fragments: 4 tiles of 16 m-cols, K=64 in two halves (32 VGPR)
  bf16x8 bfr[4][2];
#pragma unroll
  for (int t = 0; t < 4; ++t)
#pragma unroll
    for (int h = 0; h < 2; ++h)
      bfr[t][h] = *reinterpret_cast<const bf16x8*>(
          &eb[(size_t)(m0 + t * 16 + lr) * ZD + h * 32 + lg * 8]);

  f32x4 minv[4];
#pragma unroll
  for (int t = 0; t < 4; ++t)
    minv[t] = (f32x4){3.4e38f, 3.4e38f, 3.4e38f, 3.4e38f};

  auto stage = [&](char* dst, const char* src) {
    __builtin_amdgcn_global_load_lds(
        (const __attribute__((address_space(1))) unsigned int*)src,
        (__attribute__((address_space(3))) unsigned int*)dst, 16, 0, 0);
    __builtin_amdgcn_global_load_lds(
        (const __attribute__((address_space(1))) unsigned int*)(src + 1024),
        (__attribute__((address_space(3))) unsigned int*)(dst + 1024), 16, 0, 0);
  };

  const float* znp = zn + nb0;
  const int x0 = (lg * 16) ^ ((lr & 7) << 4);  // swizzled 16B slot, K-half 0

  stage(ldst0, zsrc);
  zsrc += 8192;
  __syncthreads();  // vmcnt(0) drain before s_barrier

  for (int it = 0; it < NITER; ++it) {
    const char* lbase = (it & 1) ? (const char*)&zlds[1][0] : (const char*)&zlds[0][0];
    if (it + 1 < NITER) {
      stage((it & 1) ? ldst0 : ldst1, zsrc);
      zsrc += 8192;
    }
#pragma unroll
    for (int s = 0; s < 4; ++s) {
      const int rb = (s * 16 + lr) * 128;
      bf16x8 a0 = *reinterpret_cast<const bf16x8*>(lbase + rb + x0);
      bf16x8 a1 = *reinterpret_cast<const bf16x8*>(lbase + rb + (x0 ^ 64));
      f32x4 znv = *reinterpret_cast<const f32x4*>(znp + s * 16 + lg * 4);
#pragma unroll
      for (int t = 0; t < 4; ++t) {
        // acc = zn[n] + sum_k z_n[k] * (-2 e_m[k])
        f32x4 acc = __builtin_amdgcn_mfma_f32_16x16x32_bf16(a0, bfr[t][0], znv, 0, 0, 0);
        acc = __builtin_amdgcn_mfma_f32_16x16x32_bf16(a1, bfr[t][1], acc, 0, 0, 0);
#pragma unroll
        for (int r = 0; r < 4; ++r) minv[t][r] = fminf(minv[t][r], acc[r]);
      }
    }
    znp += NROWS;
    __syncthreads();  // next-stage landed; prev buf safe to overwrite
  }

  // per-wave reduction: in-lane over 4 rows, cross-lane over 4 row-groups
#pragma unroll
  for (int t = 0; t < 4; ++t) {
    float v = fminf(fminf(minv[t][0], minv[t][1]), fminf(minv[t][2], minv[t][3]));
    v = fminf(v, __shfl_xor(v, 16, 64));
    v = fminf(v, __shfl_xor(v, 32, 64));
    if (lg == 0) partial[(size_t)cb * MM + m0 + t * 16 + lr] = v;
  }
}

// ---------------------------------------------------------------------------
// finalize1: 32 blocks x 256 m-cols: bsum[b] = sum_m ( en[m] + min_c partial )
// finalize2: out = (sum_b bsum[b]) / M
// ---------------------------------------------------------------------------
__global__ __launch_bounds__(256) void finalize1(const float* __restrict__ partial,
                                                 const float* __restrict__ en,
                                                 double* __restrict__ bsum) {
  const int m = blockIdx.x * 256 + threadIdx.x;
  float mv = partial[m];
#pragma unroll
  for (int c = 1; c < NCHUNKS; ++c)
    mv = fminf(mv, partial[(size_t)c * MM + m]);
  double s = (double)(mv + en[m]);
  __shared__ double sred[256];
  sred[threadIdx.x] = s;
  __syncthreads();
  for (int off = 128; off > 0; off >>= 1) {
    if ((int)threadIdx.x < off) sred[threadIdx.x] += sred[threadIdx.x + off];
    __syncthreads();
  }
  if (threadIdx.x == 0) bsum[blockIdx.x] = sred[0];
}

__global__ __launch_bounds__(64) void finalize2(const double* __restrict__ bsum,
                                                float* __restrict__ out) {
  double s = (threadIdx.x < MM / 256) ? bsum[threadIdx.x] : 0.0;
  s += __shfl_xor(s, 1, 64);
  s += __shfl_xor(s, 2, 64);
  s += __shfl_xor(s, 4, 64);
  s += __shfl_xor(s, 8, 64);
  s += __shfl_xor(s, 16, 64);
  s += __shfl_xor(s, 32, 64);
  if (threadIdx.x == 0) out[0] = (float)(s / (double)MM);
}

extern "C" void kernel_launch(void* const* d_in, const int* in_sizes, int n_in,
                              void* d_out, int out_size, void* d_ws, size_t ws_size,
                              hipStream_t stream) {
  const float* z = (const float*)d_in[0];  // (N, 64) f32
  const float* e = (const float*)d_in[1];  // (M, 64) f32
  float* out = (float*)d_out;

  unsigned short* zb = (unsigned short*)d_ws;          // NN*64 bf16 (4 MB)
  unsigned short* eb = zb + (size_t)NN * ZD;           // MM*64 bf16 (1 MB)
  float* zn = (float*)(eb + (size_t)MM * ZD);          // NN f32
  float* en = zn + NN;                                 // MM f32
  float* partial = en + MM;                            // NCHUNKS*MM f32
  double* bsum = (double*)(partial + (size_t)NCHUNKS * MM);  // 32 f64

  prep_z<<<NN / 32, 256, 0, stream>>>(z, zb, zn);
  prep_e<<<MM / 32, 256, 0, stream>>>(e, eb, en);
  min_dist<<<NMB * NCHUNKS, 256, 0, stream>>>(zb, eb, zn, partial);
  finalize1<<<MM / 256, 256, 0, stream>>>(partial, en, bsum);
  finalize2<<<1, 64, 0, stream>>>(bsum, out);
}

// Round 6
// 46.895 us; speedup vs baseline: 9.7562x; 1.0496x over previous
//
#include <hip/hip_runtime.h>
#include <hip/hip_bf16.h>
#include <math.h>

// Problem: N=32768, M=8192, Z=64.  loss = mean_m min_n ||tanh(z_n) - e_m||^2
#define NN 32768
#define MM 8192
#define ZD 64
#define WAVES 4
#define MW 64                  // m-cols per wave
#define MBLK (WAVES * MW)      // 256 m-cols per block
#define NMB (MM / MBLK)        // 32 m-blocks
#define NCHUNKS 32             // split of N across chunks
#define CHUNK (NN / NCHUNKS)   // 1024
#define NROWS 128              // n-rows staged per iteration
#define NITER (CHUNK / NROWS)  // 8

typedef __attribute__((ext_vector_type(8))) short bf16x8;  // 8 bf16 = 4 VGPR
typedef __attribute__((ext_vector_type(4))) float f32x4;

__device__ inline unsigned short f2bf(float f) {  // RNE f32 -> bf16 (finite)
  unsigned u = __float_as_uint(f);
  return (unsigned short)((u + 0x7fffu + ((u >> 16) & 1u)) >> 16);
}
__device__ inline float bf2f(unsigned short h) {
  return __uint_as_float(((unsigned)h) << 16);
}

// ---------------------------------------------------------------------------
// prep (fused): blocks [0, NN/32) do z-rows, blocks [NN/32, ...) do e-rows.
//   z: zb[n][k] = bf16(tanh(z[n][k])), zn[n] = sum(quantized^2)
//   e: q = bf16(e); eb[m][k] = bf16(-2*q) (exact); en[m] = sum q^2
// ---------------------------------------------------------------------------
__global__ __launch_bounds__(256) void prep(
    const float* __restrict__ z, const float* __restrict__ e,
    unsigned short* __restrict__ zb, float* __restrict__ zn,
    unsigned short* __restrict__ eb, float* __restrict__ en) {
  const int q = threadIdx.x & 7;  // 8 f32 each
  if (blockIdx.x < NN / 32) {
    const int row = blockIdx.x * 32 + (threadIdx.x >> 3);
    const size_t base = (size_t)row * ZD + q * 8;
    float4 v0 = *reinterpret_cast<const float4*>(&z[base]);
    float4 v1 = *reinterpret_cast<const float4*>(&z[base + 4]);
    float in[8] = {v0.x, v0.y, v0.z, v0.w, v1.x, v1.y, v1.z, v1.w};
    unsigned short b[8];
    float s = 0.f;
#pragma unroll
    for (int i = 0; i < 8; ++i) {
      b[i] = f2bf(tanhf(in[i]));
      float r = bf2f(b[i]);
      s += r * r;
    }
    *reinterpret_cast<bf16x8*>(&zb[base]) = *reinterpret_cast<bf16x8*>(b);
    s += __shfl_xor(s, 1, 64);
    s += __shfl_xor(s, 2, 64);
    s += __shfl_xor(s, 4, 64);
    if (q == 0) zn[row] = s;
  } else {
    const int row = (blockIdx.x - NN / 32) * 32 + (threadIdx.x >> 3);
    const size_t base = (size_t)row * ZD + q * 8;
    float4 v0 = *reinterpret_cast<const float4*>(&e[base]);
    float4 v1 = *reinterpret_cast<const float4*>(&e[base + 4]);
    float in[8] = {v0.x, v0.y, v0.z, v0.w, v1.x, v1.y, v1.z, v1.w};
    unsigned short b[8];
    float s = 0.f;
#pragma unroll
    for (int i = 0; i < 8; ++i) {
      unsigned short qb = f2bf(in[i]);
      float r = bf2f(qb);
      s += r * r;
      b[i] = f2bf(-2.f * r);  // exact: power-of-2 scale + sign
    }
    *reinterpret_cast<bf16x8*>(&eb[base]) = *reinterpret_cast<bf16x8*>(b);
    s += __shfl_xor(s, 1, 64);
    s += __shfl_xor(s, 2, 64);
    s += __shfl_xor(s, 4, 64);
    if (q == 0) en[row] = s;
  }
}

// ---------------------------------------------------------------------------
// min_dist: partial[chunk][m] = min over n-in-chunk of ( zn[n] - 2*z_n.e_m )
// 1024 blocks (4/CU), 4 waves x 64 m-cols. A-tile (128 n-rows) shared via
// LDS: global_load_lds(16B) double-buffered, XOR-swizzled (linear LDS dest +
// inverse-swizzled global source + swizzled ds_read_b128). zn folded into the
// MFMA C-operand; min3-fused scalar running min per 16-col tile.
// XCD-bijective block remap: each XCD owns 4 whole chunks.
// ---------------------------------------------------------------------------
__global__ __launch_bounds__(256, 4) void min_dist(
    const unsigned short* __restrict__ zb, const unsigned short* __restrict__ eb,
    const float* __restrict__ zn, float* __restrict__ partial) {
  __shared__ __align__(128) unsigned short zlds[2][NROWS * ZD];  // 2 x 16 KB
  // XCD-contiguous remap (grid = 1024, 1024 % 8 == 0 -> bijective):
  const int wg = ((blockIdx.x & 7) << 7) + (blockIdx.x >> 3);
  const int mb = wg & (NMB - 1);   // m-block 0..31
  const int cb = wg >> 5;          // chunk 0..31  (4 consecutive per XCD)
  const int lane = threadIdx.x & 63;
  const int wv = threadIdx.x >> 6;   // 0..3
  const int lr = lane & 15;          // fragment row/col
  const int lg = lane >> 4;          // 0..3 k-group
  const int m0 = mb * MBLK + wv * MW;
  const int nb0 = cb * CHUNK;

  // staging: 16 x 1KB pieces/iter (8 rows each), 4 per wave. Lane l writes
  // LDS byte piece*1024 + l*16 (linear dest); source is inverse-swizzled so
  // reads can apply slot ^= (row&7). Piece stride is 1024B in BOTH global
  // (8 rows x 128B contiguous) and LDS.
  const int srow = lane >> 3;           // row within piece, 0..7
  const int sslot = (lane & 7) ^ srow;  // inverse-swizzled 16B slot
  const char* zsrc = (const char*)zb + (size_t)nb0 * 128 +
                     (wv * 32 + srow) * 128 + (sslot << 4);
  char* ldst0 = (char*)&zlds[0][0] + wv * 4096;
  char* ldst1 = (char*)&zlds[1][0] + wv * 4096;

  // B fragments: 4 tiles of 16 m-cols, K=64 in two halves (32 VGPR)
  bf16x8 bfr[4][2];
#pragma unroll
  for (int t = 0; t < 4; ++t)
#pragma unroll
    for (int h = 0; h < 2; ++h)
      bfr[t][h] = *reinterpret_cast<const bf16x8*>(
          &eb[(size_t)(m0 + t * 16 + lr) * ZD + h * 32 + lg * 8]);

  float minv[4] = {3.4e38f, 3.4e38f, 3.4e38f, 3.4e38f};

  auto stage = [&](char* dst, const char* src) {
#pragma unroll
    for (int j = 0; j < 4; ++j)
      __builtin_amdgcn_global_load_lds(
          (const __attribute__((address_space(1))) unsigned int*)(src + j * 1024),
          (__attribute__((address_space(3))) unsigned int*)(dst + j * 1024),
          16, 0, 0);
  };

  const float* znp = zn + nb0;
  const int x0 = (lg * 16) ^ ((lr & 7) << 4);  // swizzled 16B slot, K-half 0

  stage(ldst0, zsrc);
  zsrc += NROWS * 128;
  __syncthreads();  // vmcnt(0) drain before s_barrier

  for (int it = 0; it < NITER; ++it) {
    const char* lbase = (it & 1) ? (const char*)&zlds[1][0] : (const char*)&zlds[0][0];
    if (it + 1 < NITER) {
      stage((it & 1) ? ldst0 : ldst1, zsrc);
      zsrc += NROWS * 128;
    }
#pragma unroll
    for (int s = 0; s < NROWS / 16; ++s) {
      const int rb = (s * 16 + lr) * 128;
      bf16x8 a0 = *reinterpret_cast<const bf16x8*>(lbase + rb + x0);
      bf16x8 a1 = *reinterpret_cast<const bf16x8*>(lbase + rb + (x0 ^ 64));
      f32x4 znv = *reinterpret_cast<const f32x4*>(znp + s * 16 + lg * 4);
#pragma unroll
      for (int t = 0; t < 4; ++t) {
        // acc = zn[n] + sum_k z_n[k] * (-2 e_m[k])
        f32x4 acc = __builtin_amdgcn_mfma_f32_16x16x32_bf16(a0, bfr[t][0], znv, 0, 0, 0);
        acc = __builtin_amdgcn_mfma_f32_16x16x32_bf16(a1, bfr[t][1], acc, 0, 0, 0);
        // two v_min3-fusable triples: min(acc[0..3], running)
        float x = fminf(fminf(acc[0], acc[1]), acc[2]);
        minv[t] = fminf(fminf(x, acc[3]), minv[t]);
      }
    }
    znp += NROWS;
    __syncthreads();  // next-stage landed; prev buf safe to overwrite
  }

  // cross-lane: min over the 4 row-groups (lg); lanes 0..15 hold col lr
#pragma unroll
  for (int t = 0; t < 4; ++t) {
    float v = minv[t];
    v = fminf(v, __shfl_xor(v, 16, 64));
    v = fminf(v, __shfl_xor(v, 32, 64));
    if (lg == 0) partial[(size_t)cb * MM + m0 + t * 16 + lr] = v;
  }
}

// ---------------------------------------------------------------------------
// finalize1: 32 blocks x 256 m-cols: bsum[b] = sum_m ( en[m] + min_c partial )
// finalize2: out = (sum_b bsum[b]) / M
// ---------------------------------------------------------------------------
__global__ __launch_bounds__(256) void finalize1(const float* __restrict__ partial,
                                                 const float* __restrict__ en,
                                                 double* __restrict__ bsum) {
  const int m = blockIdx.x * 256 + threadIdx.x;
  float mv = partial[m];
#pragma unroll
  for (int c = 1; c < NCHUNKS; ++c)
    mv = fminf(mv, partial[(size_t)c * MM + m]);
  double s = (double)(mv + en[m]);
  __shared__ double sred[256];
  sred[threadIdx.x] = s;
  __syncthreads();
  for (int off = 128; off > 0; off >>= 1) {
    if ((int)threadIdx.x < off) sred[threadIdx.x] += sred[threadIdx.x + off];
    __syncthreads();
  }
  if (threadIdx.x == 0) bsum[blockIdx.x] = sred[0];
}

__global__ __launch_bounds__(64) void finalize2(const double* __restrict__ bsum,
                                                float* __restrict__ out) {
  double s = (threadIdx.x < MM / 256) ? bsum[threadIdx.x] : 0.0;
  s += __shfl_xor(s, 1, 64);
  s += __shfl_xor(s, 2, 64);
  s += __shfl_xor(s, 4, 64);
  s += __shfl_xor(s, 8, 64);
  s += __shfl_xor(s, 16, 64);
  s += __shfl_xor(s, 32, 64);
  if (threadIdx.x == 0) out[0] = (float)(s / (double)MM);
}

extern "C" void kernel_launch(void* const* d_in, const int* in_sizes, int n_in,
                              void* d_out, int out_size, void* d_ws, size_t ws_size,
                              hipStream_t stream) {
  const float* z = (const float*)d_in[0];  // (N, 64) f32
  const float* e = (const float*)d_in[1];  // (M, 64) f32
  float* out = (float*)d_out;

  unsigned short* zb = (unsigned short*)d_ws;          // NN*64 bf16 (4 MB)
  unsigned short* eb = zb + (size_t)NN * ZD;           // MM*64 bf16 (1 MB)
  float* zn = (float*)(eb + (size_t)MM * ZD);          // NN f32
  float* en = zn + NN;                                 // MM f32
  float* partial = en + MM;                            // NCHUNKS*MM f32
  double* bsum = (double*)(partial + (size_t)NCHUNKS * MM);  // 32 f64

  prep<<<(NN + MM) / 32, 256, 0, stream>>>(z, e, zb, zn, eb, en);
  min_dist<<<NMB * NCHUNKS, 256, 0, stream>>>(zb, eb, zn, partial);
  finalize1<<<MM / 256, 256, 0, stream>>>(partial, en, bsum);
  finalize2<<<1, 64, 0, stream>>>(bsum, out);
}